// Round 3
// baseline (1604.132 us; speedup 1.0000x reference)
//
#include <hip/hip_runtime.h>
#include <math.h>

// SQVAE forward on MI355X. N=16384 rows, D=512, K=1024 codes, B=8.
// GEMMs in bf16 MFMA (16x16x32); dist GEMM hi/lo bf16 split for fp32-accurate
// logits. XCD-aware block swizzle; epilogue routed through LDS for wide stores.
#define NROWS 16384
#define DIM   512
#define KCODE 1024

typedef __attribute__((ext_vector_type(8))) __bf16 bf16x8;
typedef __attribute__((ext_vector_type(4))) float f32x4;

__device__ __forceinline__ float wave_reduce_sum(float v) {
  #pragma unroll
  for (int m = 1; m < 64; m <<= 1) v += __shfl_xor(v, m, 64);
  return v;
}
__device__ __forceinline__ float wave_reduce_max(float v) {
  #pragma unroll
  for (int m = 1; m < 64; m <<= 1) v = fmaxf(v, __shfl_xor(v, m, 64));
  return v;
}
__device__ __forceinline__ unsigned short f2bf(float f) {
  union { float f; unsigned u; } v; v.f = f;
  unsigned r = v.u + 0x7FFFu + ((v.u >> 16) & 1u);  // RNE
  return (unsigned short)(r >> 16);
}
__device__ __forceinline__ float bf2f(unsigned short h) {
  union { unsigned u; float f; } v; v.u = ((unsigned)h) << 16;
  return v.f;
}
__device__ __forceinline__ uint4 pack8(const float* x) {
  uint4 r;
  r.x = (unsigned)f2bf(x[0]) | ((unsigned)f2bf(x[1]) << 16);
  r.y = (unsigned)f2bf(x[2]) | ((unsigned)f2bf(x[3]) << 16);
  r.z = (unsigned)f2bf(x[4]) | ((unsigned)f2bf(x[5]) << 16);
  r.w = (unsigned)f2bf(x[6]) | ((unsigned)f2bf(x[7]) << 16);
  return r;
}

// ---------------------------------------------------------------------------
// bf16 MFMA GEMM, C = sum_p A_p @ B_p^T. 128x128 tile, BK=32, 4 waves (2x2),
// each wave 4x4 grid of 16x16x32 MFMA. 1D grid, XCD-swizzled: xcd=b&7 owns
// m-tiles [xcd*16, xcd*16+16), n fastest -> A slice + B resident per-XCD L2.
// Epilogue: acc -> per-wave LDS slab (stride 68) -> wide coalesced stores.
// EPI: 0 bias+relu->bf16; 1 dist logits->fp32; 2 zq->bf16 + kldc.
// AF32: A operand is fp32 (converted during staging).
// ---------------------------------------------------------------------------
template <int NPASS, int EPI, int K, int N, int LDA, int AF32>
__global__ __launch_bounds__(256) void gemm_bt(
    const void* A0v, const void* A1v, const void* A2v,
    const unsigned short* B0, const unsigned short* B1, const unsigned short* B2,
    const float* __restrict__ bias,
    const float* __restrict__ znorm, const float* __restrict__ cnorm,
    const float* __restrict__ lpq,
    const unsigned short* __restrict__ zh, const unsigned short* __restrict__ zl,
    float* __restrict__ kldc,
    unsigned short* __restrict__ outb, float* __restrict__ outf) {
  __shared__ char smem[17408];
  unsigned short* Abuf = (unsigned short*)smem;
  unsigned short* Bbuf = (unsigned short*)(smem + 8192);
  const int t = threadIdx.x;
  const int l = t & 63, w = t >> 6;
  const int wm = w >> 1, wn = w & 1;
  // XCD swizzle
  const int NTN = N / 128;
  const int b = blockIdx.x;
  const int xcd = b & 7;
  const int j = b >> 3;
  const int m0 = (xcd * 16 + j / NTN) * 128;
  const int n0 = (j % NTN) * 128;

  f32x4 acc[4][4];
  #pragma unroll
  for (int i = 0; i < 4; ++i)
    #pragma unroll
    for (int jj = 0; jj < 4; ++jj) acc[i][jj] = (f32x4){0.f, 0.f, 0.f, 0.f};

  const void* APs[3] = {A0v, A1v, A2v};
  const unsigned short* BPs[3] = {B0, B1, B2};

  #pragma unroll 1
  for (int p = 0; p < NPASS; ++p) {
    const unsigned short* gA = (const unsigned short*)APs[p];
    const float* gAf = (const float*)APs[p];
    const unsigned short* gB = BPs[p];
    for (int kt = 0; kt < K; kt += 32) {
      uint4 va[2], vb[2];
      #pragma unroll
      for (int i = 0; i < 2; ++i) {
        const int c = i * 256 + t;
        const int m = c >> 2, q = c & 3;
        if (AF32) {
          const float4 a0 = *(const float4*)&gAf[(size_t)(m0 + m) * LDA + kt + q * 8];
          const float4 a1 = *(const float4*)&gAf[(size_t)(m0 + m) * LDA + kt + q * 8 + 4];
          float vv[8] = {a0.x, a0.y, a0.z, a0.w, a1.x, a1.y, a1.z, a1.w};
          va[i] = pack8(vv);
        } else {
          va[i] = *(const uint4*)&gA[(size_t)(m0 + m) * LDA + kt + q * 8];
        }
        vb[i] = *(const uint4*)&gB[(size_t)(n0 + m) * K + kt + q * 8];
      }
      __syncthreads();
      #pragma unroll
      for (int i = 0; i < 2; ++i) {
        const int c = i * 256 + t;
        const int m = c >> 2, q = c & 3;
        const int chunk = (m >> 4) * 64 + (q << 4) + (m & 15);
        *(uint4*)&Abuf[chunk * 8] = va[i];
        *(uint4*)&Bbuf[chunk * 8] = vb[i];
      }
      __syncthreads();
      bf16x8 af[4], bfr[4];
      #pragma unroll
      for (int i = 0; i < 4; ++i) {
        af[i]  = *(const bf16x8*)&Abuf[((wm * 4 + i) * 64 + l) * 8];
        bfr[i] = *(const bf16x8*)&Bbuf[((wn * 4 + i) * 64 + l) * 8];
      }
      #pragma unroll
      for (int mi = 0; mi < 4; ++mi)
        #pragma unroll
        for (int ni = 0; ni < 4; ++ni)
          acc[mi][ni] = __builtin_amdgcn_mfma_f32_16x16x32_bf16(af[mi], bfr[ni], acc[mi][ni], 0, 0, 0);
    }
  }

  // ---- Epilogue through per-wave LDS slab (16 rows x 64 cols, stride 68) ----
  __syncthreads();  // other waves may still be reading tiles
  float* slab = (float*)(smem + w * 4352);
  const int q = l >> 4, c16 = l & 15;   // write-phase coords
  const int rr = l >> 2, cc = l & 3;    // read-phase coords (4 lanes/row)
  const float wq = (EPI >= 1) ? 0.5f / fmaxf(expf(lpq[0]), 1e-10f) : 0.f;
  float local = 0.f;

  #pragma unroll 1
  for (int mi = 0; mi < 4; ++mi) {
    #pragma unroll
    for (int ni = 0; ni < 4; ++ni)
      #pragma unroll
      for (int r = 0; r < 4; ++r)
        slab[(q * 4 + r) * 68 + ni * 16 + c16] = acc[mi][ni][r];
    __builtin_amdgcn_s_waitcnt(0);  // lgkm drain before same-wave readback
    const int m = m0 + wm * 64 + mi * 16 + rr;
    const int nb = n0 + wn * 64 + cc * 16;
    float v[16];
    #pragma unroll
    for (int k = 0; k < 4; ++k) {
      const float4 x4 = *(const float4*)&slab[rr * 68 + cc * 16 + 4 * k];
      v[4 * k + 0] = x4.x; v[4 * k + 1] = x4.y; v[4 * k + 2] = x4.z; v[4 * k + 3] = x4.w;
    }
    if (EPI == 0) {
      #pragma unroll
      for (int k = 0; k < 4; ++k) {
        const float4 b4 = *(const float4*)&bias[nb + 4 * k];
        v[4 * k + 0] = fmaxf(v[4 * k + 0] + b4.x, 0.f);
        v[4 * k + 1] = fmaxf(v[4 * k + 1] + b4.y, 0.f);
        v[4 * k + 2] = fmaxf(v[4 * k + 2] + b4.z, 0.f);
        v[4 * k + 3] = fmaxf(v[4 * k + 3] + b4.w, 0.f);
      }
      *(uint4*)&outb[(size_t)m * N + nb] = pack8(v);
      *(uint4*)&outb[(size_t)m * N + nb + 8] = pack8(v + 8);
    } else if (EPI == 1) {
      const float zn = znorm[m];
      #pragma unroll
      for (int k = 0; k < 4; ++k) {
        const float4 cn = *(const float4*)&cnorm[nb + 4 * k];
        float4 o;
        o.x = -wq * (zn + cn.x - 2.f * v[4 * k + 0]);
        o.y = -wq * (zn + cn.y - 2.f * v[4 * k + 1]);
        o.z = -wq * (zn + cn.z - 2.f * v[4 * k + 2]);
        o.w = -wq * (zn + cn.w - 2.f * v[4 * k + 3]);
        *(float4*)&outf[(size_t)m * N + nb + 4 * k] = o;
      }
    } else {
      const uint4 h0 = *(const uint4*)&zh[(size_t)m * N + nb];
      const uint4 h1 = *(const uint4*)&zh[(size_t)m * N + nb + 8];
      const uint4 l0 = *(const uint4*)&zl[(size_t)m * N + nb];
      const uint4 l1 = *(const uint4*)&zl[(size_t)m * N + nb + 8];
      const unsigned hw[8] = {h0.x, h0.y, h0.z, h0.w, h1.x, h1.y, h1.z, h1.w};
      const unsigned lw[8] = {l0.x, l0.y, l0.z, l0.w, l1.x, l1.y, l1.z, l1.w};
      #pragma unroll
      for (int i = 0; i < 8; ++i) {
        const float za = bf2f((unsigned short)(hw[i] & 0xFFFF)) + bf2f((unsigned short)(lw[i] & 0xFFFF));
        const float zb = bf2f((unsigned short)(hw[i] >> 16)) + bf2f((unsigned short)(lw[i] >> 16));
        const float da = za - v[2 * i], db = zb - v[2 * i + 1];
        local += da * da + db * db;
      }
      *(uint4*)&outb[(size_t)m * N + nb] = pack8(v);
      *(uint4*)&outb[(size_t)m * N + nb + 8] = pack8(v + 8);
    }
  }
  if (EPI == 2) {
    local = wave_reduce_sum(local) * wq;
    if (l == 0) atomicAdd(kldc, local);
  }
}

// ---------------------------------------------------------------------------
// Row LayerNorm over bf16 input [M][512]. MODE 0: bf16 out. MODE 1: hi/lo
// split out + row norm^2. MODE 2: fp32 out (final x_rec).
// ---------------------------------------------------------------------------
template <int MODE>
__global__ __launch_bounds__(256) void ln_rows(
    const unsigned short* __restrict__ X, const float* __restrict__ g,
    const float* __restrict__ be, unsigned short* __restrict__ Y,
    unsigned short* __restrict__ Yl, float* __restrict__ znorm,
    float* __restrict__ Yf) {
  const int l = threadIdx.x & 63, wv = threadIdx.x >> 6;
  float gv[8], bv[8];
  {
    const float4 a = *(const float4*)&g[l * 8];
    const float4 b = *(const float4*)&g[l * 8 + 4];
    gv[0] = a.x; gv[1] = a.y; gv[2] = a.z; gv[3] = a.w;
    gv[4] = b.x; gv[5] = b.y; gv[6] = b.z; gv[7] = b.w;
    const float4 c = *(const float4*)&be[l * 8];
    const float4 d = *(const float4*)&be[l * 8 + 4];
    bv[0] = c.x; bv[1] = c.y; bv[2] = c.z; bv[3] = c.w;
    bv[4] = d.x; bv[5] = d.y; bv[6] = d.z; bv[7] = d.w;
  }
  const int row0 = blockIdx.x * 32 + wv * 8;
  for (int rr = 0; rr < 8; ++rr) {
    const int row = row0 + rr;
    const uint4 raw = *(const uint4*)&X[(size_t)row * 512 + l * 8];
    float v[8];
    const unsigned rw[4] = {raw.x, raw.y, raw.z, raw.w};
    #pragma unroll
    for (int i = 0; i < 4; ++i) {
      v[2 * i]     = bf2f((unsigned short)(rw[i] & 0xFFFF));
      v[2 * i + 1] = bf2f((unsigned short)(rw[i] >> 16));
    }
    float s = 0.f, ss = 0.f;
    #pragma unroll
    for (int i = 0; i < 8; ++i) { s += v[i]; ss += v[i] * v[i]; }
    #pragma unroll
    for (int m = 1; m < 64; m <<= 1) {
      s += __shfl_xor(s, m, 64);
      ss += __shfl_xor(ss, m, 64);
    }
    const float mean = s * (1.f / 512.f);
    const float var = ss * (1.f / 512.f) - mean * mean;
    const float rstd = rsqrtf(var + 1e-5f);
    float y[8];
    #pragma unroll
    for (int i = 0; i < 8; ++i) y[i] = (v[i] - mean) * rstd * gv[i] + bv[i];
    if (MODE == 0) {
      *(uint4*)&Y[(size_t)row * 512 + l * 8] = pack8(y);
    } else if (MODE == 1) {
      float lo[8], ns = 0.f;
      unsigned short hx[8];
      #pragma unroll
      for (int i = 0; i < 8; ++i) {
        hx[i] = f2bf(y[i]);
        lo[i] = y[i] - bf2f(hx[i]);
        ns += y[i] * y[i];
      }
      uint4 hv;
      hv.x = (unsigned)hx[0] | ((unsigned)hx[1] << 16);
      hv.y = (unsigned)hx[2] | ((unsigned)hx[3] << 16);
      hv.z = (unsigned)hx[4] | ((unsigned)hx[5] << 16);
      hv.w = (unsigned)hx[6] | ((unsigned)hx[7] << 16);
      *(uint4*)&Y[(size_t)row * 512 + l * 8] = hv;
      *(uint4*)&Yl[(size_t)row * 512 + l * 8] = pack8(lo);
      ns = wave_reduce_sum(ns);
      if (l == 0) znorm[row] = ns;
    } else {
      float4 o0, o1;
      o0.x = y[0]; o0.y = y[1]; o0.z = y[2]; o0.w = y[3];
      o1.x = y[4]; o1.y = y[5]; o1.z = y[6]; o1.w = y[7];
      *(float4*)&Yf[(size_t)row * 512 + l * 8] = o0;
      *(float4*)&Yf[(size_t)row * 512 + l * 8 + 4] = o1;
    }
  }
}

// ---------------------------------------------------------------------------
// codebook -> hi/lo bf16 + ||c||^2
// ---------------------------------------------------------------------------
__global__ __launch_bounds__(256) void prep_cb(
    const float* __restrict__ CB, unsigned short* __restrict__ H,
    unsigned short* __restrict__ L, float* __restrict__ cnorm) {
  const int wv = threadIdx.x >> 6, l = threadIdx.x & 63;
  const int r = blockIdx.x * 4 + wv;
  const float* row = &CB[(size_t)r * 512 + l * 8];
  const float4 a = *(const float4*)row;
  const float4 b = *(const float4*)(row + 4);
  float x[8] = {a.x, a.y, a.z, a.w, b.x, b.y, b.z, b.w};
  float s = 0.f, lo[8];
  unsigned short hi[8];
  #pragma unroll
  for (int i = 0; i < 8; ++i) {
    s += x[i] * x[i];
    hi[i] = f2bf(x[i]);
    lo[i] = x[i] - bf2f(hi[i]);
  }
  uint4 hv;
  hv.x = (unsigned)hi[0] | ((unsigned)hi[1] << 16);
  hv.y = (unsigned)hi[2] | ((unsigned)hi[3] << 16);
  hv.z = (unsigned)hi[4] | ((unsigned)hi[5] << 16);
  hv.w = (unsigned)hi[6] | ((unsigned)hi[7] << 16);
  *(uint4*)&H[(size_t)r * 512 + l * 8] = hv;
  *(uint4*)&L[(size_t)r * 512 + l * 8] = pack8(lo);
  s = wave_reduce_sum(s);
  if (l == 0) cnorm[r] = s;
}

// in [R][C] fp32 -> out [C][R] bf16, LDS-tiled 32x32, coalesced both sides.
__global__ __launch_bounds__(256) void transpose_f32_bf16(
    const float* __restrict__ in, unsigned short* __restrict__ out, int R, int C) {
  __shared__ float tile[32][33];
  const int ntc = C >> 5;
  const int c0 = (blockIdx.x % ntc) * 32, r0 = (blockIdx.x / ntc) * 32;
  const int tx = threadIdx.x & 31, ty = threadIdx.x >> 5;
  #pragma unroll
  for (int i = 0; i < 4; ++i)
    tile[ty + 8 * i][tx] = in[(size_t)(r0 + ty + 8 * i) * C + c0 + tx];
  __syncthreads();
  #pragma unroll
  for (int i = 0; i < 4; ++i)
    out[(size_t)(c0 + ty + 8 * i) * R + r0 + tx] = f2bf(tile[tx][ty + 8 * i]);
}

// ---------------------------------------------------------------------------
// Softmax stats + gumbel-softmax. 1024 blocks, 4 rows/wave. Encodings bf16
// written into the first half of each logits row (pitch 2048 ushorts).
// colsum/kldd reduced per-block in LDS, then one global atomic round.
// ---------------------------------------------------------------------------
__global__ __launch_bounds__(256) void softmax_gumbel(
    const float* logits, const float* __restrict__ U, unsigned short* E,
    float* __restrict__ colsum, float* __restrict__ kldd_acc) {
  __shared__ float cs[1024];
  __shared__ float kd[4];
  const int t = threadIdx.x;
  const int wv = t >> 6, l = t & 63;
  #pragma unroll
  for (int i = 0; i < 4; ++i) cs[t + 256 * i] = 0.f;
  __syncthreads();
  float psum[16];
  #pragma unroll
  for (int i = 0; i < 16; ++i) psum[i] = 0.f;
  float kldd = 0.f;
  const int nbase = blockIdx.x * 16 + wv * 4;

  for (int it = 0; it < 4; ++it) {
    const int row = nbase + it;
    const size_t off = (size_t)row * KCODE + 4 * l;
    float v[16];
    #pragma unroll
    for (int jj = 0; jj < 4; ++jj) {
      const float4 t4 = *(const float4*)&logits[off + 256 * jj];
      v[4 * jj + 0] = t4.x; v[4 * jj + 1] = t4.y; v[4 * jj + 2] = t4.z; v[4 * jj + 3] = t4.w;
    }
    float m = v[0];
    #pragma unroll
    for (int i = 1; i < 16; ++i) m = fmaxf(m, v[i]);
    m = wave_reduce_max(m);
    float se = 0.f;
    #pragma unroll
    for (int i = 0; i < 16; ++i) se += expf(v[i] - m);
    se = wave_reduce_sum(se);
    const float lz = logf(se);
    float pl = 0.f;
    #pragma unroll
    for (int i = 0; i < 16; ++i) {
      const float lp = v[i] - m - lz;
      const float p = expf(lp);
      psum[i] += p;
      pl += p * lp;
    }
    kldd += pl;
    float y[16];
    #pragma unroll
    for (int jj = 0; jj < 4; ++jj) {
      const float4 t4 = *(const float4*)&U[off + 256 * jj];
      y[4 * jj + 0] = v[4 * jj + 0] - logf(-logf(t4.x + 1e-10f) + 1e-10f);
      y[4 * jj + 1] = v[4 * jj + 1] - logf(-logf(t4.y + 1e-10f) + 1e-10f);
      y[4 * jj + 2] = v[4 * jj + 2] - logf(-logf(t4.z + 1e-10f) + 1e-10f);
      y[4 * jj + 3] = v[4 * jj + 3] - logf(-logf(t4.w + 1e-10f) + 1e-10f);
    }
    float m2 = y[0];
    #pragma unroll
    for (int i = 1; i < 16; ++i) m2 = fmaxf(m2, y[i]);
    m2 = wave_reduce_max(m2);
    float s2 = 0.f;
    #pragma unroll
    for (int i = 0; i < 16; ++i) s2 += expf(y[i] - m2);
    s2 = wave_reduce_sum(s2);
    const float inv = 1.f / s2;
    #pragma unroll
    for (int jj = 0; jj < 4; ++jj) {
      ushort4 e;
      e.x = f2bf(expf(y[4 * jj + 0] - m2) * inv);
      e.y = f2bf(expf(y[4 * jj + 1] - m2) * inv);
      e.z = f2bf(expf(y[4 * jj + 2] - m2) * inv);
      e.w = f2bf(expf(y[4 * jj + 3] - m2) * inv);
      *(ushort4*)&E[(size_t)row * 2048 + 4 * l + 256 * jj] = e;
    }
  }
  #pragma unroll
  for (int jj = 0; jj < 4; ++jj)
    #pragma unroll
    for (int c = 0; c < 4; ++c)
      atomicAdd(&cs[256 * jj + 4 * l + c], psum[4 * jj + c]);
  kldd = wave_reduce_sum(kldd);
  if (l == 0) kd[wv] = kldd;
  __syncthreads();
  #pragma unroll
  for (int i = 0; i < 4; ++i) {
    const float vv = cs[t + 256 * i];
    if (vv != 0.f) atomicAdd(&colsum[t + 256 * i], vv);
  }
  if (t == 0) atomicAdd(kldd_acc, kd[0] + kd[1] + kd[2] + kd[3]);
}

__global__ __launch_bounds__(256) void finalize(
    const float* __restrict__ colsum, const float* __restrict__ scal,
    float* __restrict__ out) {
  const int t = threadIdx.x;
  float ent = 0.f;
  #pragma unroll
  for (int jj = 0; jj < 4; ++jj) {
    const float a = colsum[t + 256 * jj] * (1.f / 16384.f);
    ent += a * logf(a + 1e-7f);
  }
  ent = wave_reduce_sum(ent);
  __shared__ float red[4];
  if ((t & 63) == 0) red[t >> 6] = ent;
  __syncthreads();
  if (t == 0) {
    const float tot = red[0] + red[1] + red[2] + red[3];
    out[0] = (scal[0] + scal[1]) * (1.f / 8.f);
    out[1] = expf(-tot);
  }
}

extern "C" void kernel_launch(void* const* d_in, const int* in_sizes, int n_in,
                              void* d_out, int out_size, void* d_ws, size_t ws_size,
                              hipStream_t stream) {
  const float* x      = (const float*)d_in[0];
  const float* gu     = (const float*)d_in[1];
  const float* enc_w1 = (const float*)d_in[2];
  const float* enc_b1 = (const float*)d_in[3];
  const float* enc_g1 = (const float*)d_in[4];
  const float* enc_e1 = (const float*)d_in[5];
  const float* enc_w2 = (const float*)d_in[6];
  const float* enc_b2 = (const float*)d_in[7];
  const float* enc_g2 = (const float*)d_in[8];
  const float* enc_e2 = (const float*)d_in[9];
  const float* dec_w1 = (const float*)d_in[10];
  const float* dec_b1 = (const float*)d_in[11];
  const float* dec_g1 = (const float*)d_in[12];
  const float* dec_e1 = (const float*)d_in[13];
  const float* dec_w2 = (const float*)d_in[14];
  const float* dec_b2 = (const float*)d_in[15];
  const float* dec_g2 = (const float*)d_in[16];
  const float* dec_e2 = (const float*)d_in[17];
  const float* cb     = (const float*)d_in[18];
  const float* lpq    = (const float*)d_in[19];
  float* out = (float*)d_out;
  char* wsb = (char*)d_ws;

  float*          logits = (float*)(wsb + 0);                  // 64 MB
  unsigned short* Eb     = (unsigned short*)(wsb + 0);         // overlay, pitch 2048
  unsigned short* t1     = (unsigned short*)(wsb + 67108864);  // 16 MB
  unsigned short* zh     = (unsigned short*)(wsb + 83886080);  // 16 MB
  unsigned short* hq     = (unsigned short*)(wsb + 100663296); // 16 MB
  unsigned short* zl     = (unsigned short*)(wsb + 117440512); // 16 MB
  unsigned short* wt0    = (unsigned short*)(wsb + 134217728);
  unsigned short* wt1    = wt0 + 262144;
  unsigned short* wt2    = wt1 + 262144;
  unsigned short* wt3    = wt2 + 262144;
  unsigned short* cbh    = (unsigned short*)(wsb + 136314880);
  unsigned short* cbl    = (unsigned short*)(wsb + 137363456);
  unsigned short* cbT    = (unsigned short*)(wsb + 138412032);
  float*          znorm  = (float*)(wsb + 139460608);
  float*          cnorm  = (float*)(wsb + 139526144);
  float*          colsum = (float*)(wsb + 139530240);
  float*          scal   = (float*)(wsb + 139534336);

  hipMemsetAsync(colsum, 0, 4096 + 16, stream);

  prep_cb<<<256, 256, 0, stream>>>(cb, cbh, cbl, cnorm);
  transpose_f32_bf16<<<256, 256, 0, stream>>>(enc_w1, wt0, 512, 512);
  transpose_f32_bf16<<<256, 256, 0, stream>>>(enc_w2, wt1, 512, 512);
  transpose_f32_bf16<<<256, 256, 0, stream>>>(dec_w1, wt2, 512, 512);
  transpose_f32_bf16<<<256, 256, 0, stream>>>(dec_w2, wt3, 512, 512);
  transpose_f32_bf16<<<512, 256, 0, stream>>>(cb, cbT, 1024, 512);

  gemm_bt<1, 0, 512, 512, 512, 1><<<512, 256, 0, stream>>>(
      x, nullptr, nullptr, wt0, nullptr, nullptr, enc_b1,
      nullptr, nullptr, nullptr, nullptr, nullptr, nullptr, t1, nullptr);
  ln_rows<0><<<512, 256, 0, stream>>>(t1, enc_g1, enc_e1, hq, nullptr, nullptr, nullptr);
  gemm_bt<1, 0, 512, 512, 512, 0><<<512, 256, 0, stream>>>(
      hq, nullptr, nullptr, wt1, nullptr, nullptr, enc_b2,
      nullptr, nullptr, nullptr, nullptr, nullptr, nullptr, t1, nullptr);
  ln_rows<1><<<512, 256, 0, stream>>>(t1, enc_g2, enc_e2, zh, zl, znorm, nullptr);
  gemm_bt<3, 1, 512, 1024, 512, 0><<<1024, 256, 0, stream>>>(
      zh, zl, zh, cbh, cbh, cbl, nullptr,
      znorm, cnorm, lpq, nullptr, nullptr, nullptr, nullptr, logits);
  softmax_gumbel<<<1024, 256, 0, stream>>>(logits, gu, Eb, colsum, &scal[0]);
  gemm_bt<1, 2, 1024, 512, 2048, 0><<<512, 256, 0, stream>>>(
      Eb, nullptr, nullptr, cbT, nullptr, nullptr, nullptr,
      nullptr, nullptr, lpq, zh, zl, &scal[1], hq, nullptr);
  gemm_bt<1, 0, 512, 512, 512, 0><<<512, 256, 0, stream>>>(
      hq, nullptr, nullptr, wt2, nullptr, nullptr, dec_b1,
      nullptr, nullptr, nullptr, nullptr, nullptr, nullptr, t1, nullptr);
  ln_rows<0><<<512, 256, 0, stream>>>(t1, dec_g1, dec_e1, zl, nullptr, nullptr, nullptr);
  gemm_bt<1, 0, 512, 512, 512, 0><<<512, 256, 0, stream>>>(
      zl, nullptr, nullptr, wt3, nullptr, nullptr, dec_b2,
      nullptr, nullptr, nullptr, nullptr, nullptr, nullptr, t1, nullptr);
  ln_rows<2><<<512, 256, 0, stream>>>(t1, dec_g2, dec_e2, nullptr, nullptr, nullptr, out);
  finalize<<<1, 256, 0, stream>>>(colsum, scal, out + 8388608);
}

// Round 4
// 755.989 us; speedup vs baseline: 2.1219x; 2.1219x over previous
//
#include <hip/hip_runtime.h>
#include <math.h>

// SQVAE forward on MI355X. N=16384 rows, D=512, K=1024 codes, B=8.
// GEMMs in bf16 MFMA (16x16x32); dist GEMM hi/lo bf16 split for fp32-accurate
// logits. XCD-aware block swizzle; epilogue routed through LDS for wide stores.
// R4: epilogue fully unrolled (R3's `#pragma unroll 1` runtime-indexed acc[]
// -> scratch spill -> 4 GB/dispatch scratch traffic, MfmaUtil 3%).
#define NROWS 16384
#define DIM   512
#define KCODE 1024

typedef __attribute__((ext_vector_type(8))) __bf16 bf16x8;
typedef __attribute__((ext_vector_type(4))) float f32x4;

__device__ __forceinline__ float wave_reduce_sum(float v) {
  #pragma unroll
  for (int m = 1; m < 64; m <<= 1) v += __shfl_xor(v, m, 64);
  return v;
}
__device__ __forceinline__ float wave_reduce_max(float v) {
  #pragma unroll
  for (int m = 1; m < 64; m <<= 1) v = fmaxf(v, __shfl_xor(v, m, 64));
  return v;
}
__device__ __forceinline__ unsigned short f2bf(float f) {
  union { float f; unsigned u; } v; v.f = f;
  unsigned r = v.u + 0x7FFFu + ((v.u >> 16) & 1u);  // RNE
  return (unsigned short)(r >> 16);
}
__device__ __forceinline__ float bf2f(unsigned short h) {
  union { unsigned u; float f; } v; v.u = ((unsigned)h) << 16;
  return v.f;
}
__device__ __forceinline__ uint4 pack8(const float* x) {
  uint4 r;
  r.x = (unsigned)f2bf(x[0]) | ((unsigned)f2bf(x[1]) << 16);
  r.y = (unsigned)f2bf(x[2]) | ((unsigned)f2bf(x[3]) << 16);
  r.z = (unsigned)f2bf(x[4]) | ((unsigned)f2bf(x[5]) << 16);
  r.w = (unsigned)f2bf(x[6]) | ((unsigned)f2bf(x[7]) << 16);
  return r;
}

// ---------------------------------------------------------------------------
// bf16 MFMA GEMM, C = sum_p A_p @ B_p^T. 128x128 tile, BK=32, 4 waves (2x2),
// each wave 4x4 grid of 16x16x32 MFMA. 1D grid, XCD-swizzled: xcd=b&7 owns
// m-tiles [xcd*16, xcd*16+16), n fastest -> A slice + B resident per-XCD L2.
// Epilogue: acc -> per-wave LDS slab (stride 68) -> wide coalesced stores.
// EPI: 0 bias+relu->bf16; 1 dist logits->fp32; 2 zq->bf16 + kldc.
// AF32: A operand is fp32 (converted during staging).
// ---------------------------------------------------------------------------
template <int NPASS, int EPI, int K, int N, int LDA, int AF32>
__global__ __launch_bounds__(256) void gemm_bt(
    const void* A0v, const void* A1v, const void* A2v,
    const unsigned short* B0, const unsigned short* B1, const unsigned short* B2,
    const float* __restrict__ bias,
    const float* __restrict__ znorm, const float* __restrict__ cnorm,
    const float* __restrict__ lpq,
    const unsigned short* __restrict__ zh, const unsigned short* __restrict__ zl,
    float* __restrict__ kldc,
    unsigned short* __restrict__ outb, float* __restrict__ outf) {
  __shared__ char smem[17408];
  unsigned short* Abuf = (unsigned short*)smem;
  unsigned short* Bbuf = (unsigned short*)(smem + 8192);
  const int t = threadIdx.x;
  const int l = t & 63, w = t >> 6;
  const int wm = w >> 1, wn = w & 1;
  // XCD swizzle
  const int NTN = N / 128;
  const int b = blockIdx.x;
  const int xcd = b & 7;
  const int j = b >> 3;
  const int m0 = (xcd * 16 + j / NTN) * 128;
  const int n0 = (j % NTN) * 128;

  f32x4 acc[4][4];
  #pragma unroll
  for (int i = 0; i < 4; ++i)
    #pragma unroll
    for (int jj = 0; jj < 4; ++jj) acc[i][jj] = (f32x4){0.f, 0.f, 0.f, 0.f};

  const void* APs[3] = {A0v, A1v, A2v};
  const unsigned short* BPs[3] = {B0, B1, B2};

  #pragma unroll 1
  for (int p = 0; p < NPASS; ++p) {
    const unsigned short* gA = (const unsigned short*)APs[p];
    const float* gAf = (const float*)APs[p];
    const unsigned short* gB = BPs[p];
    for (int kt = 0; kt < K; kt += 32) {
      uint4 va[2], vb[2];
      #pragma unroll
      for (int i = 0; i < 2; ++i) {
        const int c = i * 256 + t;
        const int m = c >> 2, q = c & 3;
        if (AF32) {
          const float4 a0 = *(const float4*)&gAf[(size_t)(m0 + m) * LDA + kt + q * 8];
          const float4 a1 = *(const float4*)&gAf[(size_t)(m0 + m) * LDA + kt + q * 8 + 4];
          float vv[8] = {a0.x, a0.y, a0.z, a0.w, a1.x, a1.y, a1.z, a1.w};
          va[i] = pack8(vv);
        } else {
          va[i] = *(const uint4*)&gA[(size_t)(m0 + m) * LDA + kt + q * 8];
        }
        vb[i] = *(const uint4*)&gB[(size_t)(n0 + m) * K + kt + q * 8];
      }
      __syncthreads();
      #pragma unroll
      for (int i = 0; i < 2; ++i) {
        const int c = i * 256 + t;
        const int m = c >> 2, q = c & 3;
        const int chunk = (m >> 4) * 64 + (q << 4) + (m & 15);
        *(uint4*)&Abuf[chunk * 8] = va[i];
        *(uint4*)&Bbuf[chunk * 8] = vb[i];
      }
      __syncthreads();
      bf16x8 af[4], bfr[4];
      #pragma unroll
      for (int i = 0; i < 4; ++i) {
        af[i]  = *(const bf16x8*)&Abuf[((wm * 4 + i) * 64 + l) * 8];
        bfr[i] = *(const bf16x8*)&Bbuf[((wn * 4 + i) * 64 + l) * 8];
      }
      #pragma unroll
      for (int mi = 0; mi < 4; ++mi)
        #pragma unroll
        for (int ni = 0; ni < 4; ++ni)
          acc[mi][ni] = __builtin_amdgcn_mfma_f32_16x16x32_bf16(af[mi], bfr[ni], acc[mi][ni], 0, 0, 0);
    }
  }

  // ---- Epilogue through per-wave LDS slab (16 rows x 64 cols, stride 68) ----
  // FULLY UNROLLED: acc[][] indices must be compile-time constants, else the
  // accumulators spill to scratch and the K-loop does global-memory RMW (R3).
  float* slab = (float*)(smem + w * 4352);
  const int q = l >> 4, c16 = l & 15;   // write-phase coords
  const int rr = l >> 2, cc = l & 3;    // read-phase coords (4 lanes/row)
  const float wq = (EPI >= 1) ? 0.5f / fmaxf(expf(lpq[0]), 1e-10f) : 0.f;
  float local = 0.f;

  #pragma unroll
  for (int mi = 0; mi < 4; ++mi) {
    __syncthreads();  // slab region free (staging buffers / previous iter)
    #pragma unroll
    for (int ni = 0; ni < 4; ++ni)
      #pragma unroll
      for (int r = 0; r < 4; ++r)
        slab[(q * 4 + r) * 68 + ni * 16 + c16] = acc[mi][ni][r];
    __syncthreads();  // cross-lane LDS visibility + compiler ordering barrier
    const int m = m0 + wm * 64 + mi * 16 + rr;
    const int nb = n0 + wn * 64 + cc * 16;
    float v[16];
    #pragma unroll
    for (int k = 0; k < 4; ++k) {
      const float4 x4 = *(const float4*)&slab[rr * 68 + cc * 16 + 4 * k];
      v[4 * k + 0] = x4.x; v[4 * k + 1] = x4.y; v[4 * k + 2] = x4.z; v[4 * k + 3] = x4.w;
    }
    if (EPI == 0) {
      #pragma unroll
      for (int k = 0; k < 4; ++k) {
        const float4 b4 = *(const float4*)&bias[nb + 4 * k];
        v[4 * k + 0] = fmaxf(v[4 * k + 0] + b4.x, 0.f);
        v[4 * k + 1] = fmaxf(v[4 * k + 1] + b4.y, 0.f);
        v[4 * k + 2] = fmaxf(v[4 * k + 2] + b4.z, 0.f);
        v[4 * k + 3] = fmaxf(v[4 * k + 3] + b4.w, 0.f);
      }
      *(uint4*)&outb[(size_t)m * N + nb] = pack8(v);
      *(uint4*)&outb[(size_t)m * N + nb + 8] = pack8(v + 8);
    } else if (EPI == 1) {
      const float zn = znorm[m];
      #pragma unroll
      for (int k = 0; k < 4; ++k) {
        const float4 cn = *(const float4*)&cnorm[nb + 4 * k];
        float4 o;
        o.x = -wq * (zn + cn.x - 2.f * v[4 * k + 0]);
        o.y = -wq * (zn + cn.y - 2.f * v[4 * k + 1]);
        o.z = -wq * (zn + cn.z - 2.f * v[4 * k + 2]);
        o.w = -wq * (zn + cn.w - 2.f * v[4 * k + 3]);
        *(float4*)&outf[(size_t)m * N + nb + 4 * k] = o;
      }
    } else {
      const uint4 h0 = *(const uint4*)&zh[(size_t)m * N + nb];
      const uint4 h1 = *(const uint4*)&zh[(size_t)m * N + nb + 8];
      const uint4 l0 = *(const uint4*)&zl[(size_t)m * N + nb];
      const uint4 l1 = *(const uint4*)&zl[(size_t)m * N + nb + 8];
      const unsigned hw[8] = {h0.x, h0.y, h0.z, h0.w, h1.x, h1.y, h1.z, h1.w};
      const unsigned lw[8] = {l0.x, l0.y, l0.z, l0.w, l1.x, l1.y, l1.z, l1.w};
      #pragma unroll
      for (int i = 0; i < 8; ++i) {
        const float za = bf2f((unsigned short)(hw[i] & 0xFFFF)) + bf2f((unsigned short)(lw[i] & 0xFFFF));
        const float zb = bf2f((unsigned short)(hw[i] >> 16)) + bf2f((unsigned short)(lw[i] >> 16));
        const float da = za - v[2 * i], db = zb - v[2 * i + 1];
        local += da * da + db * db;
      }
      *(uint4*)&outb[(size_t)m * N + nb] = pack8(v);
      *(uint4*)&outb[(size_t)m * N + nb + 8] = pack8(v + 8);
    }
  }
  if (EPI == 2) {
    local = wave_reduce_sum(local) * wq;
    if (l == 0) atomicAdd(kldc, local);
  }
}

// ---------------------------------------------------------------------------
// Row LayerNorm over bf16 input [M][512]. MODE 0: bf16 out. MODE 1: hi/lo
// split out + row norm^2. MODE 2: fp32 out (final x_rec).
// ---------------------------------------------------------------------------
template <int MODE>
__global__ __launch_bounds__(256) void ln_rows(
    const unsigned short* __restrict__ X, const float* __restrict__ g,
    const float* __restrict__ be, unsigned short* __restrict__ Y,
    unsigned short* __restrict__ Yl, float* __restrict__ znorm,
    float* __restrict__ Yf) {
  const int l = threadIdx.x & 63, wv = threadIdx.x >> 6;
  float gv[8], bv[8];
  {
    const float4 a = *(const float4*)&g[l * 8];
    const float4 b = *(const float4*)&g[l * 8 + 4];
    gv[0] = a.x; gv[1] = a.y; gv[2] = a.z; gv[3] = a.w;
    gv[4] = b.x; gv[5] = b.y; gv[6] = b.z; gv[7] = b.w;
    const float4 c = *(const float4*)&be[l * 8];
    const float4 d = *(const float4*)&be[l * 8 + 4];
    bv[0] = c.x; bv[1] = c.y; bv[2] = c.z; bv[3] = c.w;
    bv[4] = d.x; bv[5] = d.y; bv[6] = d.z; bv[7] = d.w;
  }
  const int row0 = blockIdx.x * 32 + wv * 8;
  for (int rr = 0; rr < 8; ++rr) {
    const int row = row0 + rr;
    const uint4 raw = *(const uint4*)&X[(size_t)row * 512 + l * 8];
    float v[8];
    const unsigned rw[4] = {raw.x, raw.y, raw.z, raw.w};
    #pragma unroll
    for (int i = 0; i < 4; ++i) {
      v[2 * i]     = bf2f((unsigned short)(rw[i] & 0xFFFF));
      v[2 * i + 1] = bf2f((unsigned short)(rw[i] >> 16));
    }
    float s = 0.f, ss = 0.f;
    #pragma unroll
    for (int i = 0; i < 8; ++i) { s += v[i]; ss += v[i] * v[i]; }
    #pragma unroll
    for (int m = 1; m < 64; m <<= 1) {
      s += __shfl_xor(s, m, 64);
      ss += __shfl_xor(ss, m, 64);
    }
    const float mean = s * (1.f / 512.f);
    const float var = ss * (1.f / 512.f) - mean * mean;
    const float rstd = rsqrtf(var + 1e-5f);
    float y[8];
    #pragma unroll
    for (int i = 0; i < 8; ++i) y[i] = (v[i] - mean) * rstd * gv[i] + bv[i];
    if (MODE == 0) {
      *(uint4*)&Y[(size_t)row * 512 + l * 8] = pack8(y);
    } else if (MODE == 1) {
      float lo[8], ns = 0.f;
      unsigned short hx[8];
      #pragma unroll
      for (int i = 0; i < 8; ++i) {
        hx[i] = f2bf(y[i]);
        lo[i] = y[i] - bf2f(hx[i]);
        ns += y[i] * y[i];
      }
      uint4 hv;
      hv.x = (unsigned)hx[0] | ((unsigned)hx[1] << 16);
      hv.y = (unsigned)hx[2] | ((unsigned)hx[3] << 16);
      hv.z = (unsigned)hx[4] | ((unsigned)hx[5] << 16);
      hv.w = (unsigned)hx[6] | ((unsigned)hx[7] << 16);
      *(uint4*)&Y[(size_t)row * 512 + l * 8] = hv;
      *(uint4*)&Yl[(size_t)row * 512 + l * 8] = pack8(lo);
      ns = wave_reduce_sum(ns);
      if (l == 0) znorm[row] = ns;
    } else {
      float4 o0, o1;
      o0.x = y[0]; o0.y = y[1]; o0.z = y[2]; o0.w = y[3];
      o1.x = y[4]; o1.y = y[5]; o1.z = y[6]; o1.w = y[7];
      *(float4*)&Yf[(size_t)row * 512 + l * 8] = o0;
      *(float4*)&Yf[(size_t)row * 512 + l * 8 + 4] = o1;
    }
  }
}

// ---------------------------------------------------------------------------
// codebook -> hi/lo bf16 + ||c||^2
// ---------------------------------------------------------------------------
__global__ __launch_bounds__(256) void prep_cb(
    const float* __restrict__ CB, unsigned short* __restrict__ H,
    unsigned short* __restrict__ L, float* __restrict__ cnorm) {
  const int wv = threadIdx.x >> 6, l = threadIdx.x & 63;
  const int r = blockIdx.x * 4 + wv;
  const float* row = &CB[(size_t)r * 512 + l * 8];
  const float4 a = *(const float4*)row;
  const float4 b = *(const float4*)(row + 4);
  float x[8] = {a.x, a.y, a.z, a.w, b.x, b.y, b.z, b.w};
  float s = 0.f, lo[8];
  unsigned short hi[8];
  #pragma unroll
  for (int i = 0; i < 8; ++i) {
    s += x[i] * x[i];
    hi[i] = f2bf(x[i]);
    lo[i] = x[i] - bf2f(hi[i]);
  }
  uint4 hv;
  hv.x = (unsigned)hi[0] | ((unsigned)hi[1] << 16);
  hv.y = (unsigned)hi[2] | ((unsigned)hi[3] << 16);
  hv.z = (unsigned)hi[4] | ((unsigned)hi[5] << 16);
  hv.w = (unsigned)hi[6] | ((unsigned)hi[7] << 16);
  *(uint4*)&H[(size_t)r * 512 + l * 8] = hv;
  *(uint4*)&L[(size_t)r * 512 + l * 8] = pack8(lo);
  s = wave_reduce_sum(s);
  if (l == 0) cnorm[r] = s;
}

// in [R][C] fp32 -> out [C][R] bf16, LDS-tiled 32x32, coalesced both sides.
__global__ __launch_bounds__(256) void transpose_f32_bf16(
    const float* __restrict__ in, unsigned short* __restrict__ out, int R, int C) {
  __shared__ float tile[32][33];
  const int ntc = C >> 5;
  const int c0 = (blockIdx.x % ntc) * 32, r0 = (blockIdx.x / ntc) * 32;
  const int tx = threadIdx.x & 31, ty = threadIdx.x >> 5;
  #pragma unroll
  for (int i = 0; i < 4; ++i)
    tile[ty + 8 * i][tx] = in[(size_t)(r0 + ty + 8 * i) * C + c0 + tx];
  __syncthreads();
  #pragma unroll
  for (int i = 0; i < 4; ++i)
    out[(size_t)(c0 + ty + 8 * i) * R + r0 + tx] = f2bf(tile[tx][ty + 8 * i]);
}

// ---------------------------------------------------------------------------
// Softmax stats + gumbel-softmax. 1024 blocks, 4 rows/wave. Encodings bf16
// written into the first half of each logits row (pitch 2048 ushorts).
// colsum/kldd reduced per-block in LDS, then one global atomic round.
// ---------------------------------------------------------------------------
__global__ __launch_bounds__(256) void softmax_gumbel(
    const float* logits, const float* __restrict__ U, unsigned short* E,
    float* __restrict__ colsum, float* __restrict__ kldd_acc) {
  __shared__ float cs[1024];
  __shared__ float kd[4];
  const int t = threadIdx.x;
  const int wv = t >> 6, l = t & 63;
  #pragma unroll
  for (int i = 0; i < 4; ++i) cs[t + 256 * i] = 0.f;
  __syncthreads();
  float psum[16];
  #pragma unroll
  for (int i = 0; i < 16; ++i) psum[i] = 0.f;
  float kldd = 0.f;
  const int nbase = blockIdx.x * 16 + wv * 4;

  for (int it = 0; it < 4; ++it) {
    const int row = nbase + it;
    const size_t off = (size_t)row * KCODE + 4 * l;
    float v[16];
    #pragma unroll
    for (int jj = 0; jj < 4; ++jj) {
      const float4 t4 = *(const float4*)&logits[off + 256 * jj];
      v[4 * jj + 0] = t4.x; v[4 * jj + 1] = t4.y; v[4 * jj + 2] = t4.z; v[4 * jj + 3] = t4.w;
    }
    float m = v[0];
    #pragma unroll
    for (int i = 1; i < 16; ++i) m = fmaxf(m, v[i]);
    m = wave_reduce_max(m);
    float se = 0.f;
    #pragma unroll
    for (int i = 0; i < 16; ++i) se += expf(v[i] - m);
    se = wave_reduce_sum(se);
    const float lz = logf(se);
    float pl = 0.f;
    #pragma unroll
    for (int i = 0; i < 16; ++i) {
      const float lp = v[i] - m - lz;
      const float p = expf(lp);
      psum[i] += p;
      pl += p * lp;
    }
    kldd += pl;
    float y[16];
    #pragma unroll
    for (int jj = 0; jj < 4; ++jj) {
      const float4 t4 = *(const float4*)&U[off + 256 * jj];
      y[4 * jj + 0] = v[4 * jj + 0] - logf(-logf(t4.x + 1e-10f) + 1e-10f);
      y[4 * jj + 1] = v[4 * jj + 1] - logf(-logf(t4.y + 1e-10f) + 1e-10f);
      y[4 * jj + 2] = v[4 * jj + 2] - logf(-logf(t4.z + 1e-10f) + 1e-10f);
      y[4 * jj + 3] = v[4 * jj + 3] - logf(-logf(t4.w + 1e-10f) + 1e-10f);
    }
    float m2 = y[0];
    #pragma unroll
    for (int i = 1; i < 16; ++i) m2 = fmaxf(m2, y[i]);
    m2 = wave_reduce_max(m2);
    float s2 = 0.f;
    #pragma unroll
    for (int i = 0; i < 16; ++i) s2 += expf(y[i] - m2);
    s2 = wave_reduce_sum(s2);
    const float inv = 1.f / s2;
    #pragma unroll
    for (int jj = 0; jj < 4; ++jj) {
      ushort4 e;
      e.x = f2bf(expf(y[4 * jj + 0] - m2) * inv);
      e.y = f2bf(expf(y[4 * jj + 1] - m2) * inv);
      e.z = f2bf(expf(y[4 * jj + 2] - m2) * inv);
      e.w = f2bf(expf(y[4 * jj + 3] - m2) * inv);
      *(ushort4*)&E[(size_t)row * 2048 + 4 * l + 256 * jj] = e;
    }
  }
  #pragma unroll
  for (int jj = 0; jj < 4; ++jj)
    #pragma unroll
    for (int c = 0; c < 4; ++c)
      atomicAdd(&cs[256 * jj + 4 * l + c], psum[4 * jj + c]);
  kldd = wave_reduce_sum(kldd);
  if (l == 0) kd[wv] = kldd;
  __syncthreads();
  #pragma unroll
  for (int i = 0; i < 4; ++i) {
    const float vv = cs[t + 256 * i];
    if (vv != 0.f) atomicAdd(&colsum[t + 256 * i], vv);
  }
  if (t == 0) atomicAdd(kldd_acc, kd[0] + kd[1] + kd[2] + kd[3]);
}

__global__ __launch_bounds__(256) void finalize(
    const float* __restrict__ colsum, const float* __restrict__ scal,
    float* __restrict__ out) {
  const int t = threadIdx.x;
  float ent = 0.f;
  #pragma unroll
  for (int jj = 0; jj < 4; ++jj) {
    const float a = colsum[t + 256 * jj] * (1.f / 16384.f);
    ent += a * logf(a + 1e-7f);
  }
  ent = wave_reduce_sum(ent);
  __shared__ float red[4];
  if ((t & 63) == 0) red[t >> 6] = ent;
  __syncthreads();
  if (t == 0) {
    const float tot = red[0] + red[1] + red[2] + red[3];
    out[0] = (scal[0] + scal[1]) * (1.f / 8.f);
    out[1] = expf(-tot);
  }
}

extern "C" void kernel_launch(void* const* d_in, const int* in_sizes, int n_in,
                              void* d_out, int out_size, void* d_ws, size_t ws_size,
                              hipStream_t stream) {
  const float* x      = (const float*)d_in[0];
  const float* gu     = (const float*)d_in[1];
  const float* enc_w1 = (const float*)d_in[2];
  const float* enc_b1 = (const float*)d_in[3];
  const float* enc_g1 = (const float*)d_in[4];
  const float* enc_e1 = (const float*)d_in[5];
  const float* enc_w2 = (const float*)d_in[6];
  const float* enc_b2 = (const float*)d_in[7];
  const float* enc_g2 = (const float*)d_in[8];
  const float* enc_e2 = (const float*)d_in[9];
  const float* dec_w1 = (const float*)d_in[10];
  const float* dec_b1 = (const float*)d_in[11];
  const float* dec_g1 = (const float*)d_in[12];
  const float* dec_e1 = (const float*)d_in[13];
  const float* dec_w2 = (const float*)d_in[14];
  const float* dec_b2 = (const float*)d_in[15];
  const float* dec_g2 = (const float*)d_in[16];
  const float* dec_e2 = (const float*)d_in[17];
  const float* cb     = (const float*)d_in[18];
  const float* lpq    = (const float*)d_in[19];
  float* out = (float*)d_out;
  char* wsb = (char*)d_ws;

  float*          logits = (float*)(wsb + 0);                  // 64 MB
  unsigned short* Eb     = (unsigned short*)(wsb + 0);         // overlay, pitch 2048
  unsigned short* t1     = (unsigned short*)(wsb + 67108864);  // 16 MB
  unsigned short* zh     = (unsigned short*)(wsb + 83886080);  // 16 MB
  unsigned short* hq     = (unsigned short*)(wsb + 100663296); // 16 MB
  unsigned short* zl     = (unsigned short*)(wsb + 117440512); // 16 MB
  unsigned short* wt0    = (unsigned short*)(wsb + 134217728);
  unsigned short* wt1    = wt0 + 262144;
  unsigned short* wt2    = wt1 + 262144;
  unsigned short* wt3    = wt2 + 262144;
  unsigned short* cbh    = (unsigned short*)(wsb + 136314880);
  unsigned short* cbl    = (unsigned short*)(wsb + 137363456);
  unsigned short* cbT    = (unsigned short*)(wsb + 138412032);
  float*          znorm  = (float*)(wsb + 139460608);
  float*          cnorm  = (float*)(wsb + 139526144);
  float*          colsum = (float*)(wsb + 139530240);
  float*          scal   = (float*)(wsb + 139534336);

  hipMemsetAsync(colsum, 0, 4096 + 16, stream);

  prep_cb<<<256, 256, 0, stream>>>(cb, cbh, cbl, cnorm);
  transpose_f32_bf16<<<256, 256, 0, stream>>>(enc_w1, wt0, 512, 512);
  transpose_f32_bf16<<<256, 256, 0, stream>>>(enc_w2, wt1, 512, 512);
  transpose_f32_bf16<<<256, 256, 0, stream>>>(dec_w1, wt2, 512, 512);
  transpose_f32_bf16<<<256, 256, 0, stream>>>(dec_w2, wt3, 512, 512);
  transpose_f32_bf16<<<512, 256, 0, stream>>>(cb, cbT, 1024, 512);

  gemm_bt<1, 0, 512, 512, 512, 1><<<512, 256, 0, stream>>>(
      x, nullptr, nullptr, wt0, nullptr, nullptr, enc_b1,
      nullptr, nullptr, nullptr, nullptr, nullptr, nullptr, t1, nullptr);
  ln_rows<0><<<512, 256, 0, stream>>>(t1, enc_g1, enc_e1, hq, nullptr, nullptr, nullptr);
  gemm_bt<1, 0, 512, 512, 512, 0><<<512, 256, 0, stream>>>(
      hq, nullptr, nullptr, wt1, nullptr, nullptr, enc_b2,
      nullptr, nullptr, nullptr, nullptr, nullptr, nullptr, t1, nullptr);
  ln_rows<1><<<512, 256, 0, stream>>>(t1, enc_g2, enc_e2, zh, zl, znorm, nullptr);
  gemm_bt<3, 1, 512, 1024, 512, 0><<<1024, 256, 0, stream>>>(
      zh, zl, zh, cbh, cbh, cbl, nullptr,
      znorm, cnorm, lpq, nullptr, nullptr, nullptr, nullptr, logits);
  softmax_gumbel<<<1024, 256, 0, stream>>>(logits, gu, Eb, colsum, &scal[0]);
  gemm_bt<1, 2, 1024, 512, 2048, 0><<<512, 256, 0, stream>>>(
      Eb, nullptr, nullptr, cbT, nullptr, nullptr, nullptr,
      nullptr, nullptr, lpq, zh, zl, &scal[1], hq, nullptr);
  gemm_bt<1, 0, 512, 512, 512, 0><<<512, 256, 0, stream>>>(
      hq, nullptr, nullptr, wt2, nullptr, nullptr, dec_b1,
      nullptr, nullptr, nullptr, nullptr, nullptr, nullptr, t1, nullptr);
  ln_rows<0><<<512, 256, 0, stream>>>(t1, dec_g1, dec_e1, zl, nullptr, nullptr, nullptr);
  gemm_bt<1, 0, 512, 512, 512, 0><<<512, 256, 0, stream>>>(
      zl, nullptr, nullptr, wt3, nullptr, nullptr, dec_b2,
      nullptr, nullptr, nullptr, nullptr, nullptr, nullptr, t1, nullptr);
  ln_rows<2><<<512, 256, 0, stream>>>(t1, dec_g2, dec_e2, nullptr, nullptr, nullptr, out);
  finalize<<<1, 256, 0, stream>>>(colsum, scal, out + 8388608);
}

// Round 5
// 537.012 us; speedup vs baseline: 2.9871x; 1.4078x over previous
//
#include <hip/hip_runtime.h>
#include <math.h>

// SQVAE forward on MI355X. N=16384 rows, D=512, K=1024 codes, B=8.
// R5: K-loop uses global_load_lds (width 16) in fragment-linear order (m97
// pattern); epilogue stores fully coalesced (16 lanes x 16B contiguous).
#define NROWS 16384
#define DIM   512
#define KCODE 1024

typedef __attribute__((ext_vector_type(8))) __bf16 bf16x8;
typedef __attribute__((ext_vector_type(4))) float f32x4;

__device__ __forceinline__ float wave_reduce_sum(float v) {
  #pragma unroll
  for (int m = 1; m < 64; m <<= 1) v += __shfl_xor(v, m, 64);
  return v;
}
__device__ __forceinline__ float wave_reduce_max(float v) {
  #pragma unroll
  for (int m = 1; m < 64; m <<= 1) v = fmaxf(v, __shfl_xor(v, m, 64));
  return v;
}
__device__ __forceinline__ unsigned short f2bf(float f) {
  union { float f; unsigned u; } v; v.f = f;
  unsigned r = v.u + 0x7FFFu + ((v.u >> 16) & 1u);  // RNE
  return (unsigned short)(r >> 16);
}
__device__ __forceinline__ float bf2f(unsigned short h) {
  union { unsigned u; float f; } v; v.u = ((unsigned)h) << 16;
  return v.f;
}
__device__ __forceinline__ uint4 pack8(const float* x) {
  uint4 r;
  r.x = (unsigned)f2bf(x[0]) | ((unsigned)f2bf(x[1]) << 16);
  r.y = (unsigned)f2bf(x[2]) | ((unsigned)f2bf(x[3]) << 16);
  r.z = (unsigned)f2bf(x[4]) | ((unsigned)f2bf(x[5]) << 16);
  r.w = (unsigned)f2bf(x[6]) | ((unsigned)f2bf(x[7]) << 16);
  return r;
}

// async global->LDS, 16B per lane. LDS dst must be wave-uniform base;
// HW writes base + lane*16.
__device__ __forceinline__ void glds16(const void* g, void* lds) {
  __builtin_amdgcn_global_load_lds(
      (const __attribute__((address_space(1))) unsigned int*)g,
      (__attribute__((address_space(3))) unsigned int*)lds, 16, 0, 0);
}

// ---------------------------------------------------------------------------
// bf16 MFMA GEMM, C = sum_p A_p @ B_p^T. A: [M][K] pitch LDA, B: [N][K] pitch
// K, both bf16. 128x128 tile, BK=32, 4 waves (2x2), each wave 4x4 of
// 16x16x32 MFMA. Staging: global_load_lds in fragment-linear chunk order
// (chunk g = 16 rows x 32 k; lane l stages row g*16+(l&15), k (l>>4)*8 -> LDS
// chunk*1024 + l*16; identical address stream the ds_read_b128 consumes).
// XCD swizzle: xcd=b&7 owns a contiguous 1/8 of m-tiles, n fastest.
// EPI: 0 bias+relu->bf16; 1 dist logits->fp32; 2 zq->bf16 + kldc.
// ---------------------------------------------------------------------------
template <int NPASS, int EPI, int K, int N, int LDA>
__global__ __launch_bounds__(256) void gemm_bt(
    const unsigned short* A0, const unsigned short* A1, const unsigned short* A2,
    const unsigned short* B0, const unsigned short* B1, const unsigned short* B2,
    const float* __restrict__ bias,
    const float* __restrict__ znorm, const float* __restrict__ cnorm,
    const float* __restrict__ lpq,
    const unsigned short* __restrict__ zh, const unsigned short* __restrict__ zl,
    float* __restrict__ kldc,
    unsigned short* __restrict__ outb, float* __restrict__ outf) {
  __shared__ char smem[17408];
  unsigned short* Abuf = (unsigned short*)smem;           // 8 KB, chunks 0..7
  unsigned short* Bbuf = (unsigned short*)(smem + 8192);  // 8 KB
  const int t = threadIdx.x;
  const int l = t & 63, w = t >> 6;
  const int wm = w >> 1, wn = w & 1;
  const int NTN = N / 128;
  const int b = blockIdx.x;
  const int xcd = b & 7;
  const int j = b >> 3;
  const int m0 = (xcd * 16 + j / NTN) * 128;
  const int n0 = (j % NTN) * 128;

  f32x4 acc[4][4];
  #pragma unroll
  for (int i = 0; i < 4; ++i)
    #pragma unroll
    for (int jj = 0; jj < 4; ++jj) acc[i][jj] = (f32x4){0.f, 0.f, 0.f, 0.f};

  // staging geometry: wave w stages chunks {w, w+4} of A and of B
  const int row_lo = w * 16 + (l & 15);        // tile-row for chunk w
  const int row_hi = (w + 4) * 16 + (l & 15);  // tile-row for chunk w+4
  const int kcol = (l >> 4) * 8;               // k-offset within BK
  char* ldsA0 = (char*)Abuf + w * 1024;
  char* ldsA1 = (char*)Abuf + (w + 4) * 1024;
  char* ldsB0 = (char*)Bbuf + w * 1024;
  char* ldsB1 = (char*)Bbuf + (w + 4) * 1024;

  const unsigned short* APs[3] = {A0, A1, A2};
  const unsigned short* BPs[3] = {B0, B1, B2};

  #pragma unroll 1
  for (int p = 0; p < NPASS; ++p) {
    const unsigned short* aA0 = APs[p] + (size_t)(m0 + row_lo) * LDA + kcol;
    const unsigned short* aA1 = APs[p] + (size_t)(m0 + row_hi) * LDA + kcol;
    const unsigned short* aB0 = BPs[p] + (size_t)(n0 + row_lo) * K + kcol;
    const unsigned short* aB1 = BPs[p] + (size_t)(n0 + row_hi) * K + kcol;
    for (int kt = 0; kt < K; kt += 32) {
      glds16(aA0 + kt, ldsA0);
      glds16(aA1 + kt, ldsA1);
      glds16(aB0 + kt, ldsB0);
      glds16(aB1 + kt, ldsB1);
      __syncthreads();  // vmcnt drain: staged data visible
      bf16x8 af[4], bfr[4];
      #pragma unroll
      for (int i = 0; i < 4; ++i) {
        af[i]  = *(const bf16x8*)&Abuf[((wm * 4 + i) * 64 + l) * 8];
        bfr[i] = *(const bf16x8*)&Bbuf[((wn * 4 + i) * 64 + l) * 8];
      }
      #pragma unroll
      for (int mi = 0; mi < 4; ++mi)
        #pragma unroll
        for (int ni = 0; ni < 4; ++ni)
          acc[mi][ni] = __builtin_amdgcn_mfma_f32_16x16x32_bf16(af[mi], bfr[ni], acc[mi][ni], 0, 0, 0);
      __syncthreads();  // all reads done before next stage overwrites
    }
  }

  // ---- Epilogue via per-wave LDS slab (16 rows x 64 cols, stride 68) ----
  // Write phase: MFMA C-layout scatter. Read phase: lane l -> row (l>>4),
  // float4 at col (l&15)*4 -> 16 consecutive lanes cover 256B contiguous.
  float* slab = (float*)(smem + w * 4352);
  const int q = l >> 4, c16 = l & 15;
  const int rr = l >> 4, c4 = (l & 15) * 4;
  const float wq = (EPI >= 1) ? 0.5f / fmaxf(expf(lpq[0]), 1e-10f) : 0.f;
  float local = 0.f;

  #pragma unroll
  for (int mi = 0; mi < 4; ++mi) {
    __syncthreads();
    #pragma unroll
    for (int ni = 0; ni < 4; ++ni)
      #pragma unroll
      for (int r = 0; r < 4; ++r)
        slab[(q * 4 + r) * 68 + ni * 16 + c16] = acc[mi][ni][r];
    __syncthreads();
    #pragma unroll
    for (int pp = 0; pp < 4; ++pp) {
      const int row = pp * 4 + rr;  // 0..15
      const float4 v4 = *(const float4*)&slab[row * 68 + c4];
      float v[4] = {v4.x, v4.y, v4.z, v4.w};
      const int m = m0 + wm * 64 + mi * 16 + row;
      const int nc = n0 + wn * 64 + c4;
      if (EPI == 0) {
        const float4 b4 = *(const float4*)&bias[nc];
        v[0] = fmaxf(v[0] + b4.x, 0.f);
        v[1] = fmaxf(v[1] + b4.y, 0.f);
        v[2] = fmaxf(v[2] + b4.z, 0.f);
        v[3] = fmaxf(v[3] + b4.w, 0.f);
        uint2 st;
        st.x = (unsigned)f2bf(v[0]) | ((unsigned)f2bf(v[1]) << 16);
        st.y = (unsigned)f2bf(v[2]) | ((unsigned)f2bf(v[3]) << 16);
        *(uint2*)&outb[(size_t)m * N + nc] = st;
      } else if (EPI == 1) {
        const float zn = znorm[m];
        const float4 cn = *(const float4*)&cnorm[nc];
        float4 o;
        o.x = -wq * (zn + cn.x - 2.f * v[0]);
        o.y = -wq * (zn + cn.y - 2.f * v[1]);
        o.z = -wq * (zn + cn.z - 2.f * v[2]);
        o.w = -wq * (zn + cn.w - 2.f * v[3]);
        *(float4*)&outf[(size_t)m * N + nc] = o;
      } else {
        const uint2 h2 = *(const uint2*)&zh[(size_t)m * N + nc];
        const uint2 l2 = *(const uint2*)&zl[(size_t)m * N + nc];
        const float z0 = bf2f((unsigned short)(h2.x & 0xFFFF)) + bf2f((unsigned short)(l2.x & 0xFFFF));
        const float z1 = bf2f((unsigned short)(h2.x >> 16))    + bf2f((unsigned short)(l2.x >> 16));
        const float z2 = bf2f((unsigned short)(h2.y & 0xFFFF)) + bf2f((unsigned short)(l2.y & 0xFFFF));
        const float z3 = bf2f((unsigned short)(h2.y >> 16))    + bf2f((unsigned short)(l2.y >> 16));
        const float d0 = z0 - v[0], d1 = z1 - v[1], d2 = z2 - v[2], d3 = z3 - v[3];
        local += d0 * d0 + d1 * d1 + d2 * d2 + d3 * d3;
        uint2 st;
        st.x = (unsigned)f2bf(v[0]) | ((unsigned)f2bf(v[1]) << 16);
        st.y = (unsigned)f2bf(v[2]) | ((unsigned)f2bf(v[3]) << 16);
        *(uint2*)&outb[(size_t)m * N + nc] = st;
      }
    }
  }
  if (EPI == 2) {
    local = wave_reduce_sum(local) * wq;
    if (l == 0) atomicAdd(kldc, local);
  }
}

// ---------------------------------------------------------------------------
// Row LayerNorm over bf16 input [M][512]. MODE 0: bf16 out. MODE 1: hi/lo
// split out + row norm^2. MODE 2: fp32 out (final x_rec).
// ---------------------------------------------------------------------------
template <int MODE>
__global__ __launch_bounds__(256) void ln_rows(
    const unsigned short* __restrict__ X, const float* __restrict__ g,
    const float* __restrict__ be, unsigned short* __restrict__ Y,
    unsigned short* __restrict__ Yl, float* __restrict__ znorm,
    float* __restrict__ Yf) {
  const int l = threadIdx.x & 63, wv = threadIdx.x >> 6;
  float gv[8], bv[8];
  {
    const float4 a = *(const float4*)&g[l * 8];
    const float4 b = *(const float4*)&g[l * 8 + 4];
    gv[0] = a.x; gv[1] = a.y; gv[2] = a.z; gv[3] = a.w;
    gv[4] = b.x; gv[5] = b.y; gv[6] = b.z; gv[7] = b.w;
    const float4 c = *(const float4*)&be[l * 8];
    const float4 d = *(const float4*)&be[l * 8 + 4];
    bv[0] = c.x; bv[1] = c.y; bv[2] = c.z; bv[3] = c.w;
    bv[4] = d.x; bv[5] = d.y; bv[6] = d.z; bv[7] = d.w;
  }
  const int row0 = blockIdx.x * 32 + wv * 8;
  for (int rr = 0; rr < 8; ++rr) {
    const int row = row0 + rr;
    const uint4 raw = *(const uint4*)&X[(size_t)row * 512 + l * 8];
    float v[8];
    const unsigned rw[4] = {raw.x, raw.y, raw.z, raw.w};
    #pragma unroll
    for (int i = 0; i < 4; ++i) {
      v[2 * i]     = bf2f((unsigned short)(rw[i] & 0xFFFF));
      v[2 * i + 1] = bf2f((unsigned short)(rw[i] >> 16));
    }
    float s = 0.f, ss = 0.f;
    #pragma unroll
    for (int i = 0; i < 8; ++i) { s += v[i]; ss += v[i] * v[i]; }
    #pragma unroll
    for (int m = 1; m < 64; m <<= 1) {
      s += __shfl_xor(s, m, 64);
      ss += __shfl_xor(ss, m, 64);
    }
    const float mean = s * (1.f / 512.f);
    const float var = ss * (1.f / 512.f) - mean * mean;
    const float rstd = rsqrtf(var + 1e-5f);
    float y[8];
    #pragma unroll
    for (int i = 0; i < 8; ++i) y[i] = (v[i] - mean) * rstd * gv[i] + bv[i];
    if (MODE == 0) {
      *(uint4*)&Y[(size_t)row * 512 + l * 8] = pack8(y);
    } else if (MODE == 1) {
      float lo[8], ns = 0.f;
      unsigned short hx[8];
      #pragma unroll
      for (int i = 0; i < 8; ++i) {
        hx[i] = f2bf(y[i]);
        lo[i] = y[i] - bf2f(hx[i]);
        ns += y[i] * y[i];
      }
      uint4 hv;
      hv.x = (unsigned)hx[0] | ((unsigned)hx[1] << 16);
      hv.y = (unsigned)hx[2] | ((unsigned)hx[3] << 16);
      hv.z = (unsigned)hx[4] | ((unsigned)hx[5] << 16);
      hv.w = (unsigned)hx[6] | ((unsigned)hx[7] << 16);
      *(uint4*)&Y[(size_t)row * 512 + l * 8] = hv;
      *(uint4*)&Yl[(size_t)row * 512 + l * 8] = pack8(lo);
      ns = wave_reduce_sum(ns);
      if (l == 0) znorm[row] = ns;
    } else {
      float4 o0, o1;
      o0.x = y[0]; o0.y = y[1]; o0.z = y[2]; o0.w = y[3];
      o1.x = y[4]; o1.y = y[5]; o1.z = y[6]; o1.w = y[7];
      *(float4*)&Yf[(size_t)row * 512 + l * 8] = o0;
      *(float4*)&Yf[(size_t)row * 512 + l * 8 + 4] = o1;
    }
  }
}

// ---------------------------------------------------------------------------
// Prep kernels.
// ---------------------------------------------------------------------------
__global__ __launch_bounds__(256) void convert_f32_bf16(
    const float* __restrict__ X, unsigned short* __restrict__ Y) {
  const size_t i = ((size_t)blockIdx.x * 256 + threadIdx.x) * 8;
  const float4 a = *(const float4*)&X[i];
  const float4 b = *(const float4*)&X[i + 4];
  float v[8] = {a.x, a.y, a.z, a.w, b.x, b.y, b.z, b.w};
  *(uint4*)&Y[i] = pack8(v);
}

// codebook -> hi/lo bf16 + ||c||^2
__global__ __launch_bounds__(256) void prep_cb(
    const float* __restrict__ CB, unsigned short* __restrict__ H,
    unsigned short* __restrict__ L, float* __restrict__ cnorm) {
  const int wv = threadIdx.x >> 6, l = threadIdx.x & 63;
  const int r = blockIdx.x * 4 + wv;
  const float* row = &CB[(size_t)r * 512 + l * 8];
  const float4 a = *(const float4*)row;
  const float4 b = *(const float4*)(row + 4);
  float x[8] = {a.x, a.y, a.z, a.w, b.x, b.y, b.z, b.w};
  float s = 0.f, lo[8];
  unsigned short hi[8];
  #pragma unroll
  for (int i = 0; i < 8; ++i) {
    s += x[i] * x[i];
    hi[i] = f2bf(x[i]);
    lo[i] = x[i] - bf2f(hi[i]);
  }
  uint4 hv;
  hv.x = (unsigned)hi[0] | ((unsigned)hi[1] << 16);
  hv.y = (unsigned)hi[2] | ((unsigned)hi[3] << 16);
  hv.z = (unsigned)hi[4] | ((unsigned)hi[5] << 16);
  hv.w = (unsigned)hi[6] | ((unsigned)hi[7] << 16);
  *(uint4*)&H[(size_t)r * 512 + l * 8] = hv;
  *(uint4*)&L[(size_t)r * 512 + l * 8] = pack8(lo);
  s = wave_reduce_sum(s);
  if (l == 0) cnorm[r] = s;
}

// in [R][C] fp32 -> out [C][R] bf16, LDS-tiled 32x32, coalesced both sides.
__global__ __launch_bounds__(256) void transpose_f32_bf16(
    const float* __restrict__ in, unsigned short* __restrict__ out, int R, int C) {
  __shared__ float tile[32][33];
  const int ntc = C >> 5;
  const int c0 = (blockIdx.x % ntc) * 32, r0 = (blockIdx.x / ntc) * 32;
  const int tx = threadIdx.x & 31, ty = threadIdx.x >> 5;
  #pragma unroll
  for (int i = 0; i < 4; ++i)
    tile[ty + 8 * i][tx] = in[(size_t)(r0 + ty + 8 * i) * C + c0 + tx];
  __syncthreads();
  #pragma unroll
  for (int i = 0; i < 4; ++i)
    out[(size_t)(c0 + ty + 8 * i) * R + r0 + tx] = f2bf(tile[tx][ty + 8 * i]);
}

// ---------------------------------------------------------------------------
// Softmax stats + gumbel-softmax. 1024 blocks, 4 rows/wave. Encodings bf16
// written into the first half of each logits row (pitch 2048 ushorts).
// colsum/kldd reduced per-block in LDS, then one global atomic round.
// ---------------------------------------------------------------------------
__global__ __launch_bounds__(256) void softmax_gumbel(
    const float* logits, const float* __restrict__ U, unsigned short* E,
    float* __restrict__ colsum, float* __restrict__ kldd_acc) {
  __shared__ float cs[1024];
  __shared__ float kd[4];
  const int t = threadIdx.x;
  const int wv = t >> 6, l = t & 63;
  #pragma unroll
  for (int i = 0; i < 4; ++i) cs[t + 256 * i] = 0.f;
  __syncthreads();
  float psum[16];
  #pragma unroll
  for (int i = 0; i < 16; ++i) psum[i] = 0.f;
  float kldd = 0.f;
  const int nbase = blockIdx.x * 16 + wv * 4;

  for (int it = 0; it < 4; ++it) {
    const int row = nbase + it;
    const size_t off = (size_t)row * KCODE + 4 * l;
    float v[16];
    #pragma unroll
    for (int jj = 0; jj < 4; ++jj) {
      const float4 t4 = *(const float4*)&logits[off + 256 * jj];
      v[4 * jj + 0] = t4.x; v[4 * jj + 1] = t4.y; v[4 * jj + 2] = t4.z; v[4 * jj + 3] = t4.w;
    }
    float m = v[0];
    #pragma unroll
    for (int i = 1; i < 16; ++i) m = fmaxf(m, v[i]);
    m = wave_reduce_max(m);
    float se = 0.f;
    #pragma unroll
    for (int i = 0; i < 16; ++i) se += expf(v[i] - m);
    se = wave_reduce_sum(se);
    const float lz = logf(se);
    float pl = 0.f;
    #pragma unroll
    for (int i = 0; i < 16; ++i) {
      const float lp = v[i] - m - lz;
      const float p = expf(lp);
      psum[i] += p;
      pl += p * lp;
    }
    kldd += pl;
    float y[16];
    #pragma unroll
    for (int jj = 0; jj < 4; ++jj) {
      const float4 t4 = *(const float4*)&U[off + 256 * jj];
      y[4 * jj + 0] = v[4 * jj + 0] - logf(-logf(t4.x + 1e-10f) + 1e-10f);
      y[4 * jj + 1] = v[4 * jj + 1] - logf(-logf(t4.y + 1e-10f) + 1e-10f);
      y[4 * jj + 2] = v[4 * jj + 2] - logf(-logf(t4.z + 1e-10f) + 1e-10f);
      y[4 * jj + 3] = v[4 * jj + 3] - logf(-logf(t4.w + 1e-10f) + 1e-10f);
    }
    float m2 = y[0];
    #pragma unroll
    for (int i = 1; i < 16; ++i) m2 = fmaxf(m2, y[i]);
    m2 = wave_reduce_max(m2);
    float s2 = 0.f;
    #pragma unroll
    for (int i = 0; i < 16; ++i) s2 += expf(y[i] - m2);
    s2 = wave_reduce_sum(s2);
    const float inv = 1.f / s2;
    #pragma unroll
    for (int jj = 0; jj < 4; ++jj) {
      ushort4 e;
      e.x = f2bf(expf(y[4 * jj + 0] - m2) * inv);
      e.y = f2bf(expf(y[4 * jj + 1] - m2) * inv);
      e.z = f2bf(expf(y[4 * jj + 2] - m2) * inv);
      e.w = f2bf(expf(y[4 * jj + 3] - m2) * inv);
      *(ushort4*)&E[(size_t)row * 2048 + 4 * l + 256 * jj] = e;
    }
  }
  #pragma unroll
  for (int jj = 0; jj < 4; ++jj)
    #pragma unroll
    for (int c = 0; c < 4; ++c)
      atomicAdd(&cs[256 * jj + 4 * l + c], psum[4 * jj + c]);
  kldd = wave_reduce_sum(kldd);
  if (l == 0) kd[wv] = kldd;
  __syncthreads();
  #pragma unroll
  for (int i = 0; i < 4; ++i) {
    const float vv = cs[t + 256 * i];
    if (vv != 0.f) atomicAdd(&colsum[t + 256 * i], vv);
  }
  if (t == 0) atomicAdd(kldd_acc, kd[0] + kd[1] + kd[2] + kd[3]);
}

__global__ __launch_bounds__(256) void finalize(
    const float* __restrict__ colsum, const float* __restrict__ scal,
    float* __restrict__ out) {
  const int t = threadIdx.x;
  float ent = 0.f;
  #pragma unroll
  for (int jj = 0; jj < 4; ++jj) {
    const float a = colsum[t + 256 * jj] * (1.f / 16384.f);
    ent += a * logf(a + 1e-7f);
  }
  ent = wave_reduce_sum(ent);
  __shared__ float red[4];
  if ((t & 63) == 0) red[t >> 6] = ent;
  __syncthreads();
  if (t == 0) {
    const float tot = red[0] + red[1] + red[2] + red[3];
    out[0] = (scal[0] + scal[1]) * (1.f / 8.f);
    out[1] = expf(-tot);
  }
}

extern "C" void kernel_launch(void* const* d_in, const int* in_sizes, int n_in,
                              void* d_out, int out_size, void* d_ws, size_t ws_size,
                              hipStream_t stream) {
  const float* x      = (const float*)d_in[0];
  const float* gu     = (const float*)d_in[1];
  const float* enc_w1 = (const float*)d_in[2];
  const float* enc_b1 = (const float*)d_in[3];
  const float* enc_g1 = (const float*)d_in[4];
  const float* enc_e1 = (const float*)d_in[5];
  const float* enc_w2 = (const float*)d_in[6];
  const float* enc_b2 = (const float*)d_in[7];
  const float* enc_g2 = (const float*)d_in[8];
  const float* enc_e2 = (const float*)d_in[9];
  const float* dec_w1 = (const float*)d_in[10];
  const float* dec_b1 = (const float*)d_in[11];
  const float* dec_g1 = (const float*)d_in[12];
  const float* dec_e1 = (const float*)d_in[13];
  const float* dec_w2 = (const float*)d_in[14];
  const float* dec_b2 = (const float*)d_in[15];
  const float* dec_g2 = (const float*)d_in[16];
  const float* dec_e2 = (const float*)d_in[17];
  const float* cb     = (const float*)d_in[18];
  const float* lpq    = (const float*)d_in[19];
  float* out = (float*)d_out;
  char* wsb = (char*)d_ws;

  float*          logits = (float*)(wsb + 0);                  // 64 MB
  unsigned short* Eb     = (unsigned short*)(wsb + 0);         // overlay, pitch 2048
  unsigned short* t1     = (unsigned short*)(wsb + 67108864);  // 16 MB
  unsigned short* xb     = (unsigned short*)(wsb + 83886080);  // 16 MB (xb then zh)
  unsigned short* zh     = xb;
  unsigned short* hq     = (unsigned short*)(wsb + 100663296); // 16 MB
  unsigned short* zl     = (unsigned short*)(wsb + 117440512); // 16 MB
  unsigned short* wt0    = (unsigned short*)(wsb + 134217728);
  unsigned short* wt1    = wt0 + 262144;
  unsigned short* wt2    = wt1 + 262144;
  unsigned short* wt3    = wt2 + 262144;
  unsigned short* cbh    = (unsigned short*)(wsb + 136314880);
  unsigned short* cbl    = (unsigned short*)(wsb + 137363456);
  unsigned short* cbT    = (unsigned short*)(wsb + 138412032);
  float*          znorm  = (float*)(wsb + 139460608);
  float*          cnorm  = (float*)(wsb + 139526144);
  float*          colsum = (float*)(wsb + 139530240);
  float*          scal   = (float*)(wsb + 139534336);

  hipMemsetAsync(colsum, 0, 4096 + 16, stream);

  convert_f32_bf16<<<4096, 256, 0, stream>>>(x, xb);
  prep_cb<<<256, 256, 0, stream>>>(cb, cbh, cbl, cnorm);
  transpose_f32_bf16<<<256, 256, 0, stream>>>(enc_w1, wt0, 512, 512);
  transpose_f32_bf16<<<256, 256, 0, stream>>>(enc_w2, wt1, 512, 512);
  transpose_f32_bf16<<<256, 256, 0, stream>>>(dec_w1, wt2, 512, 512);
  transpose_f32_bf16<<<256, 256, 0, stream>>>(dec_w2, wt3, 512, 512);
  transpose_f32_bf16<<<512, 256, 0, stream>>>(cb, cbT, 1024, 512);

  gemm_bt<1, 0, 512, 512, 512><<<512, 256, 0, stream>>>(
      xb, nullptr, nullptr, wt0, nullptr, nullptr, enc_b1,
      nullptr, nullptr, nullptr, nullptr, nullptr, nullptr, t1, nullptr);
  ln_rows<0><<<512, 256, 0, stream>>>(t1, enc_g1, enc_e1, hq, nullptr, nullptr, nullptr);
  gemm_bt<1, 0, 512, 512, 512><<<512, 256, 0, stream>>>(
      hq, nullptr, nullptr, wt1, nullptr, nullptr, enc_b2,
      nullptr, nullptr, nullptr, nullptr, nullptr, nullptr, t1, nullptr);
  ln_rows<1><<<512, 256, 0, stream>>>(t1, enc_g2, enc_e2, zh, zl, znorm, nullptr);
  gemm_bt<3, 1, 512, 1024, 512><<<1024, 256, 0, stream>>>(
      zh, zl, zh, cbh, cbh, cbl, nullptr,
      znorm, cnorm, lpq, nullptr, nullptr, nullptr, nullptr, logits);
  softmax_gumbel<<<1024, 256, 0, stream>>>(logits, gu, Eb, colsum, &scal[0]);
  gemm_bt<1, 2, 1024, 512, 2048><<<512, 256, 0, stream>>>(
      Eb, nullptr, nullptr, cbT, nullptr, nullptr, nullptr,
      nullptr, nullptr, lpq, zh, zl, &scal[1], hq, nullptr);
  gemm_bt<1, 0, 512, 512, 512><<<512, 256, 0, stream>>>(
      hq, nullptr, nullptr, wt2, nullptr, nullptr, dec_b1,
      nullptr, nullptr, nullptr, nullptr, nullptr, nullptr, t1, nullptr);
  ln_rows<0><<<512, 256, 0, stream>>>(t1, dec_g1, dec_e1, zl, nullptr, nullptr, nullptr);
  gemm_bt<1, 0, 512, 512, 512><<<512, 256, 0, stream>>>(
      zl, nullptr, nullptr, wt3, nullptr, nullptr, dec_b2,
      nullptr, nullptr, nullptr, nullptr, nullptr, nullptr, t1, nullptr);
  ln_rows<2><<<512, 256, 0, stream>>>(t1, dec_g2, dec_e2, nullptr, nullptr, nullptr, out);
  finalize<<<1, 256, 0, stream>>>(colsum, scal, out + 8388608);
}